// Round 9
// baseline (121.946 us; speedup 1.0000x reference)
//
#include <hip/hip_runtime.h>
#include <hip/hip_bf16.h>

// Problem constants (match reference setup_inputs).
constexpr int B   = 4;
constexpr int N   = 20000;
constexpr int E   = 320000;
constexpr int INF = 128;     // input features
constexpr int H   = 4;       // heads
constexpr int F   = 32;      // out features per head
constexpr int HF  = H * F;   // 128

typedef short bf16x8 __attribute__((ext_vector_type(8)));
typedef float f32x4  __attribute__((ext_vector_type(4)));

__device__ __forceinline__ float bflo(unsigned v) { return __uint_as_float(v << 16); }
__device__ __forceinline__ float bfhi(unsigned v) { return __uint_as_float(v & 0xffff0000u); }
__device__ __forceinline__ unsigned pack_bf2(float a, float b) {
    __hip_bfloat162 t = __float22bfloat162_rn(float2{a, b});
    return *(unsigned*)&t;
}
__device__ __forceinline__ ushort bfpack(float f) {
    __hip_bfloat16 h = __float2bfloat16(f);
    return *(ushort*)&h;
}

// ---------------------------------------------------------------- init: Wt transpose + degree histogram
// deg[] is zeroed by hipMemsetAsync before this kernel.
__global__ __launch_bounds__(256) void init_hist_kernel(const float* __restrict__ W,
                                                        __hip_bfloat16* __restrict__ wt,
                                                        const int* __restrict__ dst,
                                                        int* __restrict__ deg) {
    int i = blockIdx.x * 256 + threadIdx.x;
    if (i < HF * INF) {
        int c = i >> 7, k = i & 127;
        wt[i] = __float2bfloat16(W[k * HF + c]);
    }
    if (i < E) atomicAdd(&deg[dst[i]], 1);
}

// ---------------------------------------------------------------- MFMA GEMM + alpha fused
// h = x @ W (bf16 out, [n][b][128]) and asrc/adst per (n,b,head).
// Block: 64 rows x 128 cols, 256 threads = 4 waves; wave w owns rows w*16..w*16+15.
// LDS: wlds 32 KB (Wt bf16, [col][k]) + xbds 16 KB (x bf16 / C repack) = 48 KB (< 64 KB:
// the 64 KB variant broke under graph capture in R7).
// Swizzle everywhere: byte ^= ((row&7)<<4), row = byte>>8 (rows are 256 B).
// mfma_f32_16x16x32_bf16: A lane l: row=l&15, k=(l>>4)*8+j ; B lane l: col=l&15 ;
// C/D lane l: col=l&15, row=(l>>4)*4+reg  [m89-verified].
__global__ __launch_bounds__(256) void gemm_mfma_kernel(const float* __restrict__ x,
                                                        const __hip_bfloat16* __restrict__ wt,
                                                        const float* __restrict__ a,
                                                        __hip_bfloat16* __restrict__ hb,
                                                        float* __restrict__ asrc,
                                                        float* __restrict__ adst) {
    __shared__ ushort wlds[128 * 128];   // 32 KB
    __shared__ ushort xbds[64 * 128];    // 16 KB (x staging, then C repack)

    const int t    = threadIdx.x;
    const int row0 = blockIdx.x * 64;

    // stage Wt (2048 uint4), swizzled; col = byte>>8
    {
        const uint4* wg = (const uint4*)wt;
#pragma unroll
        for (int i = 0; i < 8; ++i) {
            const int idx  = t + i * 256;
            const uint4 v  = wg[idx];
            const int byte = idx * 16;
            const int swz  = byte ^ (((byte >> 8) & 7) << 4);
            *(uint4*)((char*)wlds + swz) = v;
        }
    }
    // stage x rows row0..row0+63: 2048 coalesced float4 reads -> bf16 uint2 (8 B) writes
    {
        const float4* xg = (const float4*)(x + (size_t)row0 * INF);
#pragma unroll
        for (int i = 0; i < 8; ++i) {
            const int idx  = t + i * 256;       // dest row = (idx*8)>>8
            const float4 q = xg[idx];
            uint2 v;
            v.x = pack_bf2(q.x, q.y);
            v.y = pack_bf2(q.z, q.w);
            const int byte = idx * 8;
            const int swz  = byte ^ (((byte >> 8) & 7) << 4);
            *(uint2*)((char*)xbds + swz) = v;
        }
    }

    const int w    = t >> 6;       // wave 0..3
    const int l    = t & 63;
    const int lrow = l & 15;       // A row within band / C,D col
    const int lgrp = l >> 4;       // k-chunk group

    __syncthreads();   // staging done

    // A-frags from swizzled LDS: row = w*16+lrow, frag kk covers k = kk*32+lgrp*8 .. +7
    bf16x8 afrag[4];
    {
        const int arow = w * 16 + lrow;
        const int rswz = (arow & 7) << 4;
#pragma unroll
        for (int kk = 0; kk < 4; ++kk) {
            const int byte = arow * 256 + kk * 64 + lgrp * 16;
            afrag[kk] = *(const bf16x8*)((const char*)xbds + (byte ^ rswz));
        }
    }

    f32x4 acc[8];
#pragma unroll
    for (int ct = 0; ct < 8; ++ct) acc[ct] = f32x4{0.f, 0.f, 0.f, 0.f};

#pragma unroll
    for (int ct = 0; ct < 8; ++ct) {
        const int col = ct * 16 + lrow;
#pragma unroll
        for (int kk = 0; kk < 4; ++kk) {
            const int byte = col * 256 + kk * 64 + lgrp * 16;
            const int swz  = byte ^ (((byte >> 8) & 7) << 4);
            const bf16x8 bfrag = *(const bf16x8*)((const char*)wlds + swz);
            acc[ct] = __builtin_amdgcn_mfma_f32_16x16x32_bf16(afrag[kk], bfrag, acc[ct], 0, 0, 0);
        }
    }

    // a-vector values for this lane's 8 cols: head = ct>>1, in-head offset = (ct&1)*16+lrow
    float a1v[8], a2v[8];
#pragma unroll
    for (int ct = 0; ct < 8; ++ct) {
        const int head = ct >> 1;
        const int coff = (ct & 1) * 16 + lrow;
        a1v[ct] = a[head * 2 * F + coff];
        a2v[ct] = a[head * 2 * F + F + coff];
    }

    // per-(head,row) partial dots + 16-lane butterfly
    float ph1[4][4], ph2[4][4];   // [head][r]
#pragma unroll
    for (int hd = 0; hd < 4; ++hd)
#pragma unroll
        for (int r = 0; r < 4; ++r) { ph1[hd][r] = 0.f; ph2[hd][r] = 0.f; }
#pragma unroll
    for (int ct = 0; ct < 8; ++ct) {
        const int hd = ct >> 1;
#pragma unroll
        for (int r = 0; r < 4; ++r) {
            ph1[hd][r] += acc[ct][r] * a1v[ct];
            ph2[hd][r] += acc[ct][r] * a2v[ct];
        }
    }
#pragma unroll
    for (int m = 1; m < 16; m <<= 1) {
#pragma unroll
        for (int hd = 0; hd < 4; ++hd)
#pragma unroll
            for (int r = 0; r < 4; ++r) {
                ph1[hd][r] += __shfl_xor(ph1[hd][r], m);
                ph2[hd][r] += __shfl_xor(ph2[hd][r], m);
            }
    }

    // alpha writes (registers only, no LDS)
#pragma unroll
    for (int r = 0; r < 4; ++r) {
        if (lrow == 0) {
            const int row = row0 + w * 16 + lgrp * 4 + r;
            const int b   = row / N;
            const int n   = row - b * N;
            const size_t ai = ((size_t)n * B + b) * H;
#pragma unroll
            for (int hd = 0; hd < 4; ++hd) {
                asrc[ai + hd] = ph1[hd][r];
                adst[ai + hd] = ph2[hd][r];
            }
        }
    }

    // C repack through LDS: bf16 into xbds (reused), then coalesced uint4 stores
    __syncthreads();   // everyone done reading wlds/xbds
#pragma unroll
    for (int ct = 0; ct < 8; ++ct) {
#pragma unroll
        for (int r = 0; r < 4; ++r) {
            const int rl   = w * 16 + lgrp * 4 + r;       // local row 0..63
            const int byte = rl * 256 + (ct * 16 + lrow) * 2;
            const int swz  = byte ^ ((rl & 7) << 4);
            *(ushort*)((char*)xbds + swz) = bfpack(acc[ct][r]);
        }
    }
    __syncthreads();
#pragma unroll
    for (int i = 0; i < 4; ++i) {
        const int c    = t + i * 256;        // 16B chunk id 0..1023
        const int rl   = c >> 4;             // local row
        const int byte = c * 16;
        const int swz  = byte ^ ((rl & 7) << 4);
        const uint4 v  = *(const uint4*)((const char*)xbds + swz);
        const int row  = row0 + rl;
        const int bb   = row / N;
        const int nn   = row - bb * N;
        *(uint4*)(hb + ((size_t)nn * B + bb) * HF + (c & 15) * 8) = v;
    }
}

// single-block scan: exactly 1000 active threads x 20 elements (N = 20000)
__global__ __launch_bounds__(1024) void scan_kernel(const int* __restrict__ deg,
                                                    int* __restrict__ offsets,
                                                    int* __restrict__ cursor) {
    __shared__ int part[1024];
    const int t = threadIdx.x;
    const bool active = (t * 20) < N;     // t < 1000

    int v[20];
    int s = 0;
    if (active) {
        const int4* dp = (const int4*)(deg + t * 20);
#pragma unroll
        for (int i = 0; i < 5; ++i) {
            int4 q = dp[i];
            v[i * 4 + 0] = q.x; v[i * 4 + 1] = q.y; v[i * 4 + 2] = q.z; v[i * 4 + 3] = q.w;
            s += q.x + q.y + q.z + q.w;
        }
    }
    part[t] = s;
    __syncthreads();
    for (int off = 1; off < 1024; off <<= 1) {
        int u = (t >= off) ? part[t - off] : 0;
        __syncthreads();
        part[t] += u;
        __syncthreads();
    }
    if (active) {
        int run = (t == 0) ? 0 : part[t - 1];
        int o[20];
#pragma unroll
        for (int i = 0; i < 20; ++i) { o[i] = run; run += v[i]; }
        int4* op = (int4*)(offsets + t * 20);
        int4* cp = (int4*)(cursor + t * 20);
#pragma unroll
        for (int i = 0; i < 5; ++i) {
            int4 q = {o[i * 4 + 0], o[i * 4 + 1], o[i * 4 + 2], o[i * 4 + 3]};
            op[i] = q;
            cp[i] = q;
        }
        if (t * 20 + 20 >= N) offsets[N] = run;   // t == 999
    }
}

__global__ __launch_bounds__(256) void fill_kernel(const int* __restrict__ ei,
                                                   int* __restrict__ cursor,
                                                   int* __restrict__ csr) {
    int e = blockIdx.x * 256 + threadIdx.x;
    if (e >= E) return;
    const int s = ei[e];          // src row
    const int d = ei[E + e];      // dst row
    const int pos = atomicAdd(&cursor[d], 1);
    csr[pos] = s;
}

// ---------------------------------------------------------------- gather/aggregate (bf16 h)
// 256 threads = 4 waves per block, one node per wave (node = blockIdx*4 + wave).
// lane l: batch b = l>>4, feature octet fq = l&15 (features 8fq..8fq+7), head = fq>>2.
// 8-wide masked main loop (no serial tail) with csr prefetch pipelined one
// iteration ahead so the uniform csr load latency hides under the h gathers.
__global__ __launch_bounds__(256) void gather_kernel(const __hip_bfloat16* __restrict__ hb,
                                                     const float* __restrict__ asrc,
                                                     const float* __restrict__ adst,
                                                     const int* __restrict__ offsets,
                                                     const int* __restrict__ csr,
                                                     float* __restrict__ out) {
    const int t  = threadIdx.x;
    const int n  = blockIdx.x * 4 + (t >> 6);
    const int l  = t & 63;
    const int b  = l >> 4;
    const int fq = l & 15;
    const int hh = fq >> 2;

    const uint4* hu = (const uint4*)hb;           // idx = s*64 + bq
    const int bq   = b * 16 + fq;
    const int aoff = b * H + hh;                  // asrc idx = s*16 + aoff
    const float ad = adst[(size_t)n * 16 + aoff];
    const int j0 = offsets[n];
    const int j1 = offsets[n + 1];
    const int deg   = j1 - j0;
    const int last  = j1 - 1;
    const int iters = (deg + 7) >> 3;

    float ac[8];
#pragma unroll
    for (int i = 0; i < 8; ++i) ac[i] = 0.f;
    float den = 0.f;

    int sc[8];
    if (iters > 0) {
#pragma unroll
        for (int i = 0; i < 8; ++i) {
            const int jj = j0 + i;
            sc[i] = csr[jj <= last ? jj : last];
        }
    }

    for (int it = 0; it < iters; ++it) {
        const int jb = j0 + it * 8;
        int sn[8];
        if (it + 1 < iters) {
#pragma unroll
            for (int i = 0; i < 8; ++i) {
                const int jj = jb + 8 + i;
                sn[i] = csr[jj <= last ? jj : last];
            }
        }

        float lv[8];
#pragma unroll
        for (int i = 0; i < 8; ++i) lv[i] = asrc[(size_t)sc[i] * 16 + aoff];
        uint4 hv[8];
#pragma unroll
        for (int i = 0; i < 8; ++i) hv[i] = hu[(size_t)sc[i] * 64 + bq];

#pragma unroll
        for (int i = 0; i < 8; ++i) {
            float tt = lv[i] + ad;
            tt = (tt >= 0.f) ? tt : 0.2f * tt;
            const float e = (jb + i < j1) ? __expf(tt) : 0.f;
            den += e;
            ac[0] += e * bflo(hv[i].x);
            ac[1] += e * bfhi(hv[i].x);
            ac[2] += e * bflo(hv[i].y);
            ac[3] += e * bfhi(hv[i].y);
            ac[4] += e * bflo(hv[i].z);
            ac[5] += e * bfhi(hv[i].z);
            ac[6] += e * bflo(hv[i].w);
            ac[7] += e * bfhi(hv[i].w);
        }

        if (it + 1 < iters) {
#pragma unroll
            for (int i = 0; i < 8; ++i) sc[i] = sn[i];
        }
    }

    const float inv = 1.0f / (den + 1e-10f);
    float4 o0 = {ac[0] * inv, ac[1] * inv, ac[2] * inv, ac[3] * inv};
    float4 o1 = {ac[4] * inv, ac[5] * inv, ac[6] * inv, ac[7] * inv};
    float4* op = (float4*)(out + ((size_t)b * N + n) * HF + fq * 8);
    op[0] = o0;
    op[1] = o1;
}

// ---------------------------------------------------------------- launch
extern "C" void kernel_launch(void* const* d_in, const int* in_sizes, int n_in,
                              void* d_out, int out_size, void* d_ws, size_t ws_size,
                              hipStream_t stream) {
    const float* x   = (const float*)d_in[0];
    const int*   ei  = (const int*)d_in[1];     // int32 (harness converts int64 -> int32)
    const float* W   = (const float*)d_in[2];
    const float* a   = (const float*)d_in[3];
    float*       out = (float*)d_out;

    // workspace carve (~25 MB total)
    char* p = (char*)d_ws;
    __hip_bfloat16* hb = (__hip_bfloat16*)p; p += (size_t)B * N * HF * sizeof(__hip_bfloat16); // 20,480,000 B
    float* asrc = (float*)p; p += (size_t)N * B * H * sizeof(float);    // 1,280,000 B
    float* adst = (float*)p; p += (size_t)N * B * H * sizeof(float);    // 1,280,000 B
    int* deg     = (int*)p;  p += 80128;
    int* offsets = (int*)p;  p += 80128;
    int* cursor  = (int*)p;  p += 80128;
    int* csr     = (int*)p;  p += (size_t)E * sizeof(int);              // 1,280,000 B
    __hip_bfloat16* wt = (__hip_bfloat16*)p; p += (size_t)HF * INF * sizeof(__hip_bfloat16); // 32,768 B

    hipMemsetAsync(deg, 0, N * sizeof(int), stream);
    init_hist_kernel<<<(E + 255) / 256, 256, 0, stream>>>(W, wt, ei + E, deg);
    gemm_mfma_kernel<<<(B * N) / 64, 256, 0, stream>>>(x, wt, a, hb, asrc, adst);
    scan_kernel<<<1, 1024, 0, stream>>>(deg, offsets, cursor);
    fill_kernel<<<(E + 255) / 256, 256, 0, stream>>>(ei, cursor, csr);
    gather_kernel<<<(N / 4), 256, 0, stream>>>(hb, asrc, adst, offsets, csr, out);
}

// Round 11
// 112.478 us; speedup vs baseline: 1.0842x; 1.0842x over previous
//
#include <hip/hip_runtime.h>
#include <hip/hip_bf16.h>

// Problem constants (match reference setup_inputs).
constexpr int B   = 4;
constexpr int N   = 20000;
constexpr int E   = 320000;
constexpr int INF = 128;     // input features
constexpr int H   = 4;       // heads
constexpr int F   = 32;      // out features per head
constexpr int HF  = H * F;   // 128

typedef short bf16x8 __attribute__((ext_vector_type(8)));
typedef float f32x4  __attribute__((ext_vector_type(4)));

__device__ __forceinline__ float bflo(unsigned v) { return __uint_as_float(v << 16); }
__device__ __forceinline__ float bfhi(unsigned v) { return __uint_as_float(v & 0xffff0000u); }
__device__ __forceinline__ unsigned pack_bf2(float a, float b) {
    __hip_bfloat162 t = __float22bfloat162_rn(float2{a, b});
    return *(unsigned*)&t;
}

// ---------------------------------------------------------------- init: Wt transpose + degree histogram
// deg[] is zeroed by hipMemsetAsync before this kernel.
__global__ __launch_bounds__(256) void init_hist_kernel(const float* __restrict__ W,
                                                        __hip_bfloat16* __restrict__ wt,
                                                        const int* __restrict__ dst,
                                                        int* __restrict__ deg) {
    int i = blockIdx.x * 256 + threadIdx.x;
    if (i < HF * INF) {
        int c = i >> 7, k = i & 127;
        wt[i] = __float2bfloat16(W[k * HF + c]);
    }
    if (i < E) atomicAdd(&deg[dst[i]], 1);
}

// ---------------------------------------------------------------- MFMA GEMM + alpha fused
// h = x @ W (bf16 out, [n][b][128]) and asrc/adst in BATCH-MAJOR [b][n][h] layout
// (so the XCD-affine gather touches only its batch's alpha block).
// Block: 64 rows x 128 cols, 256 threads = 4 waves; wave w owns rows w*16..w*16+15.
// LDS: wlds 32 KB + xbds 16 KB = 48 KB (< 64 KB: the 64 KB variant broke in R7).
// Swizzle: byte ^= (((byte>>8)&7)<<4)  (rows are 256 B).
// mfma_f32_16x16x32_bf16: A lane l: row=l&15, k=(l>>4)*8+j ; B lane l: col=l&15 ;
// C/D lane l: col=l&15, row=(l>>4)*4+reg  [m89-verified].
__global__ __launch_bounds__(256) void gemm_mfma_kernel(const float* __restrict__ x,
                                                        const __hip_bfloat16* __restrict__ wt,
                                                        const float* __restrict__ a,
                                                        __hip_bfloat16* __restrict__ hb,
                                                        float* __restrict__ asrc,
                                                        float* __restrict__ adst) {
    __shared__ ushort wlds[128 * 128];   // 32 KB
    __shared__ ushort xbds[64 * 128];    // 16 KB

    const int t    = threadIdx.x;
    const int row0 = blockIdx.x * 64;

    // stage Wt (2048 uint4), swizzled; col = byte>>8
    {
        const uint4* wg = (const uint4*)wt;
#pragma unroll
        for (int i = 0; i < 8; ++i) {
            const int idx  = t + i * 256;
            const uint4 v  = wg[idx];
            const int byte = idx * 16;
            const int swz  = byte ^ (((byte >> 8) & 7) << 4);
            *(uint4*)((char*)wlds + swz) = v;
        }
    }
    // stage x rows row0..row0+63: 2048 coalesced float4 reads -> bf16 uint2 (8 B) writes
    {
        const float4* xg = (const float4*)(x + (size_t)row0 * INF);
#pragma unroll
        for (int i = 0; i < 8; ++i) {
            const int idx  = t + i * 256;       // dest row = (idx*8)>>8
            const float4 q = xg[idx];
            uint2 v;
            v.x = pack_bf2(q.x, q.y);
            v.y = pack_bf2(q.z, q.w);
            const int byte = idx * 8;
            const int swz  = byte ^ (((byte >> 8) & 7) << 4);
            *(uint2*)((char*)xbds + swz) = v;
        }
    }

    const int w    = t >> 6;       // wave 0..3
    const int l    = t & 63;
    const int lrow = l & 15;       // A row within band / C,D col
    const int lgrp = l >> 4;       // k-chunk group

    __syncthreads();   // staging done

    // A-frags from swizzled LDS: row = w*16+lrow, frag kk covers k = kk*32+lgrp*8 .. +7
    bf16x8 afrag[4];
    {
        const int arow = w * 16 + lrow;
        const int rswz = (arow & 7) << 4;
#pragma unroll
        for (int kk = 0; kk < 4; ++kk) {
            const int byte = arow * 256 + kk * 64 + lgrp * 16;
            afrag[kk] = *(const bf16x8*)((const char*)xbds + (byte ^ rswz));
        }
    }

    f32x4 acc[8];
#pragma unroll
    for (int ct = 0; ct < 8; ++ct) acc[ct] = f32x4{0.f, 0.f, 0.f, 0.f};

#pragma unroll
    for (int ct = 0; ct < 8; ++ct) {
        const int col = ct * 16 + lrow;
#pragma unroll
        for (int kk = 0; kk < 4; ++kk) {
            const int byte = col * 256 + kk * 64 + lgrp * 16;
            const int swz  = byte ^ (((byte >> 8) & 7) << 4);
            const bf16x8 bfrag = *(const bf16x8*)((const char*)wlds + swz);
            acc[ct] = __builtin_amdgcn_mfma_f32_16x16x32_bf16(afrag[kk], bfrag, acc[ct], 0, 0, 0);
        }
    }

    // a-vector values for this lane's 8 cols: head = ct>>1, in-head offset = (ct&1)*16+lrow
    float a1v[8], a2v[8];
#pragma unroll
    for (int ct = 0; ct < 8; ++ct) {
        const int head = ct >> 1;
        const int coff = (ct & 1) * 16 + lrow;
        a1v[ct] = a[head * 2 * F + coff];
        a2v[ct] = a[head * 2 * F + F + coff];
    }

    // per-(head,row) partial dots + 16-lane butterfly
    float ph1[4][4], ph2[4][4];   // [head][r]
#pragma unroll
    for (int hd = 0; hd < 4; ++hd)
#pragma unroll
        for (int r = 0; r < 4; ++r) { ph1[hd][r] = 0.f; ph2[hd][r] = 0.f; }
#pragma unroll
    for (int ct = 0; ct < 8; ++ct) {
        const int hd = ct >> 1;
#pragma unroll
        for (int r = 0; r < 4; ++r) {
            ph1[hd][r] += acc[ct][r] * a1v[ct];
            ph2[hd][r] += acc[ct][r] * a2v[ct];
        }
    }
#pragma unroll
    for (int m = 1; m < 16; m <<= 1) {
#pragma unroll
        for (int hd = 0; hd < 4; ++hd)
#pragma unroll
            for (int r = 0; r < 4; ++r) {
                ph1[hd][r] += __shfl_xor(ph1[hd][r], m);
                ph2[hd][r] += __shfl_xor(ph2[hd][r], m);
            }
    }

    // writes (R8-style epilogue: scalar hb stores)
#pragma unroll
    for (int r = 0; r < 4; ++r) {
        const int row = row0 + w * 16 + lgrp * 4 + r;
        const int b   = row / N;
        const int n   = row - b * N;
        const size_t hbase = ((size_t)n * B + b) * HF;
#pragma unroll
        for (int ct = 0; ct < 8; ++ct)
            hb[hbase + ct * 16 + lrow] = __float2bfloat16(acc[ct][r]);
        if (lrow == 0) {
            const size_t ai = (size_t)b * (N * H) + (size_t)n * H;   // batch-major
#pragma unroll
            for (int hd = 0; hd < 4; ++hd) {
                asrc[ai + hd] = ph1[hd][r];
                adst[ai + hd] = ph2[hd][r];
            }
        }
    }
}

// single-block scan: exactly 1000 active threads x 20 elements (N = 20000)
__global__ __launch_bounds__(1024) void scan_kernel(const int* __restrict__ deg,
                                                    int* __restrict__ offsets,
                                                    int* __restrict__ cursor) {
    __shared__ int part[1024];
    const int t = threadIdx.x;
    const bool active = (t * 20) < N;     // t < 1000

    int v[20];
    int s = 0;
    if (active) {
        const int4* dp = (const int4*)(deg + t * 20);
#pragma unroll
        for (int i = 0; i < 5; ++i) {
            int4 q = dp[i];
            v[i * 4 + 0] = q.x; v[i * 4 + 1] = q.y; v[i * 4 + 2] = q.z; v[i * 4 + 3] = q.w;
            s += q.x + q.y + q.z + q.w;
        }
    }
    part[t] = s;
    __syncthreads();
    for (int off = 1; off < 1024; off <<= 1) {
        int u = (t >= off) ? part[t - off] : 0;
        __syncthreads();
        part[t] += u;
        __syncthreads();
    }
    if (active) {
        int run = (t == 0) ? 0 : part[t - 1];
        int o[20];
#pragma unroll
        for (int i = 0; i < 20; ++i) { o[i] = run; run += v[i]; }
        int4* op = (int4*)(offsets + t * 20);
        int4* cp = (int4*)(cursor + t * 20);
#pragma unroll
        for (int i = 0; i < 5; ++i) {
            int4 q = {o[i * 4 + 0], o[i * 4 + 1], o[i * 4 + 2], o[i * 4 + 3]};
            op[i] = q;
            cp[i] = q;
        }
        if (t * 20 + 20 >= N) offsets[N] = run;   // t == 999
    }
}

__global__ __launch_bounds__(256) void fill_kernel(const int* __restrict__ ei,
                                                   int* __restrict__ cursor,
                                                   int* __restrict__ csr) {
    int e = blockIdx.x * 256 + threadIdx.x;
    if (e >= E) return;
    const int s = ei[e];          // src row
    const int d = ei[E + e];      // dst row
    const int pos = atomicAdd(&cursor[d], 1);
    csr[pos] = s;
}

// ---------------------------------------------------------------- gather/aggregate (bf16 h, XCD-affine)
// Grid 20000 blocks (= B * N/4); block i: batch b = (i%8)>>1, node-quad = (i>>3)*2 + (i&1).
// With round-robin blockIdx->XCD (%8), each XCD serves ONE batch -> per-XCD L2
// working set drops 4x (20.5 -> 5.1 MB) -> compulsory FETCH ~60 MB vs 152 MB.
// Wave = one (node, batch). Lane l: edge-slot g = l>>4, feature octet fq = l&15,
// head = fq>>2. 8 edges/iter = 2 independent uint4 chains per lane; masked tail;
// final shfl_xor(16/32) cross-slot reduce; lanes g==0 write the 512 B output row.
__global__ __launch_bounds__(256) void gather_kernel(const __hip_bfloat16* __restrict__ hb,
                                                     const float* __restrict__ asrc,
                                                     const float* __restrict__ adst,
                                                     const int* __restrict__ offsets,
                                                     const int* __restrict__ csr,
                                                     float* __restrict__ out) {
    const int t  = threadIdx.x;
    const int k  = blockIdx.x & 7;
    const int b  = k >> 1;                         // batch pinned to XCD pair {2b,2b+1}
    const int n  = ((blockIdx.x >> 3) * 2 + (k & 1)) * 4 + (t >> 6);
    const int l  = t & 63;
    const int g  = l >> 4;                         // edge slot 0..3
    const int fq = l & 15;                         // feature octet
    const int hh = fq >> 2;

    const uint4* hu = (const uint4*)hb;            // idx = s*64 + rowq
    const int rowq = b * 16 + fq;
    const size_t abase = (size_t)b * (N * H);      // batch-major alpha
    const float ad = adst[abase + (size_t)n * H + hh];
    const int j0 = offsets[n];
    const int j1 = offsets[n + 1];
    const int last  = j1 - 1;
    const int iters = (j1 - j0 + 7) >> 3;

    float ac[8];
#pragma unroll
    for (int i = 0; i < 8; ++i) ac[i] = 0.f;
    float den = 0.f;

    for (int it = 0; it < iters; ++it) {
        const int jb = j0 + it * 8;
        const int jA = jb + g;
        const int jB = jA + 4;
        const int sA = csr[jA <= last ? jA : last];
        const int sB = csr[jB <= last ? jB : last];
        const float lvA = asrc[abase + (size_t)sA * H + hh];
        const float lvB = asrc[abase + (size_t)sB * H + hh];
        const uint4 vA = hu[(size_t)sA * 64 + rowq];
        const uint4 vB = hu[(size_t)sB * 64 + rowq];
        float tA = lvA + ad; tA = (tA >= 0.f) ? tA : 0.2f * tA;
        float tB = lvB + ad; tB = (tB >= 0.f) ? tB : 0.2f * tB;
        const float eA = (jA < j1) ? __expf(tA) : 0.f;
        const float eB = (jB < j1) ? __expf(tB) : 0.f;
        den += eA + eB;
        ac[0] += eA * bflo(vA.x) + eB * bflo(vB.x);
        ac[1] += eA * bfhi(vA.x) + eB * bfhi(vB.x);
        ac[2] += eA * bflo(vA.y) + eB * bflo(vB.y);
        ac[3] += eA * bfhi(vA.y) + eB * bfhi(vB.y);
        ac[4] += eA * bflo(vA.z) + eB * bflo(vB.z);
        ac[5] += eA * bfhi(vA.z) + eB * bfhi(vB.z);
        ac[6] += eA * bflo(vA.w) + eB * bflo(vB.w);
        ac[7] += eA * bfhi(vA.w) + eB * bfhi(vB.w);
    }

    // reduce across the 4 edge slots (lanes sharing fq)
    den += __shfl_xor(den, 16);
    den += __shfl_xor(den, 32);
#pragma unroll
    for (int i = 0; i < 8; ++i) {
        ac[i] += __shfl_xor(ac[i], 16);
        ac[i] += __shfl_xor(ac[i], 32);
    }

    if (g == 0) {
        const float inv = 1.0f / (den + 1e-10f);
        float4 o0 = {ac[0] * inv, ac[1] * inv, ac[2] * inv, ac[3] * inv};
        float4 o1 = {ac[4] * inv, ac[5] * inv, ac[6] * inv, ac[7] * inv};
        float4* op = (float4*)(out + ((size_t)b * N + n) * HF + fq * 8);
        op[0] = o0;
        op[1] = o1;
    }
}

// ---------------------------------------------------------------- launch
extern "C" void kernel_launch(void* const* d_in, const int* in_sizes, int n_in,
                              void* d_out, int out_size, void* d_ws, size_t ws_size,
                              hipStream_t stream) {
    const float* x   = (const float*)d_in[0];
    const int*   ei  = (const int*)d_in[1];     // int32 (harness converts int64 -> int32)
    const float* W   = (const float*)d_in[2];
    const float* a   = (const float*)d_in[3];
    float*       out = (float*)d_out;

    // workspace carve (~25 MB total)
    char* p = (char*)d_ws;
    __hip_bfloat16* hb = (__hip_bfloat16*)p; p += (size_t)B * N * HF * sizeof(__hip_bfloat16); // 20,480,000 B
    float* asrc = (float*)p; p += (size_t)N * B * H * sizeof(float);    // 1,280,000 B
    float* adst = (float*)p; p += (size_t)N * B * H * sizeof(float);    // 1,280,000 B
    int* deg     = (int*)p;  p += 80128;
    int* offsets = (int*)p;  p += 80128;
    int* cursor  = (int*)p;  p += 80128;
    int* csr     = (int*)p;  p += (size_t)E * sizeof(int);              // 1,280,000 B
    __hip_bfloat16* wt = (__hip_bfloat16*)p; p += (size_t)HF * INF * sizeof(__hip_bfloat16); // 32,768 B

    hipMemsetAsync(deg, 0, N * sizeof(int), stream);
    init_hist_kernel<<<(E + 255) / 256, 256, 0, stream>>>(W, wt, ei + E, deg);
    gemm_mfma_kernel<<<(B * N) / 64, 256, 0, stream>>>(x, wt, a, hb, asrc, adst);
    scan_kernel<<<1, 1024, 0, stream>>>(deg, offsets, cursor);
    fill_kernel<<<(E + 255) / 256, 256, 0, stream>>>(ei, cursor, csr);
    // one block per (batch, node-quad): B * N/4 = 20000 blocks
    gather_kernel<<<(N * B) / 4, 256, 0, stream>>>(hb, asrc, adst, offsets, csr, out);
}

// Round 12
// 102.807 us; speedup vs baseline: 1.1862x; 1.0941x over previous
//
#include <hip/hip_runtime.h>
#include <hip/hip_bf16.h>

// Problem constants (match reference setup_inputs).
constexpr int B    = 4;
constexpr int N    = 20000;
constexpr int E    = 320000;
constexpr int INF  = 128;     // input features
constexpr int H    = 4;       // heads
constexpr int F    = 32;      // out features per head
constexpr int HF   = H * F;   // 128
constexpr int CSRP = E + 15 * N;   // 620000: CSR padded to per-node multiples of 16

typedef short bf16x8 __attribute__((ext_vector_type(8)));
typedef float f32x4  __attribute__((ext_vector_type(4)));
typedef float f32x2  __attribute__((ext_vector_type(2)));

__device__ __forceinline__ float bflo(unsigned v) { return __uint_as_float(v << 16); }
__device__ __forceinline__ float bfhi(unsigned v) { return __uint_as_float(v & 0xffff0000u); }
__device__ __forceinline__ f32x2 unp2(unsigned v) {
    return f32x2{__uint_as_float(v << 16), __uint_as_float(v & 0xffff0000u)};
}
__device__ __forceinline__ unsigned pack_bf2(float a, float b) {
    __hip_bfloat162 t = __float22bfloat162_rn(float2{a, b});
    return *(unsigned*)&t;
}

// ---------------------------------------------------------------- init: zero deg + zero padded csr + Wt transpose
__global__ __launch_bounds__(256) void initz_kernel(const float* __restrict__ W,
                                                    __hip_bfloat16* __restrict__ wt,
                                                    int* __restrict__ deg,
                                                    int* __restrict__ csr) {
    int i = blockIdx.x * 256 + threadIdx.x;
    if (i < CSRP / 4) ((int4*)csr)[i] = int4{0, 0, 0, 0};
    if (i < N) deg[i] = 0;
    if (i < HF * INF) {
        int c = i >> 7, k = i & 127;
        wt[i] = __float2bfloat16(W[k * HF + c]);
    }
}

// ---------------------------------------------------------------- MFMA GEMM + alpha + edge histogram fused
// h = x @ W (bf16 out, [n][b][128]) and asrc/adst in BATCH-MAJOR [b][n][h] layout.
// Grid is exactly 1250 blocks x 256 threads = E: thread (blk,t) also histograms edge blk*256+t.
// Block: 64 rows x 128 cols, 4 waves. LDS: wlds 32 KB + xbds 16 KB = 48 KB (<64 KB; R7 lesson).
// Swizzle: byte ^= (((byte>>8)&7)<<4) (rows are 256 B).
// mfma_f32_16x16x32_bf16: A lane l: row=l&15, k=(l>>4)*8+j ; B lane l: col=l&15 ;
// C/D lane l: col=l&15, row=(l>>4)*4+reg  [m89-verified].
__global__ __launch_bounds__(256) void gemm_mfma_kernel(const float* __restrict__ x,
                                                        const __hip_bfloat16* __restrict__ wt,
                                                        const float* __restrict__ a,
                                                        const int* __restrict__ dst,
                                                        int* __restrict__ deg,
                                                        __hip_bfloat16* __restrict__ hb,
                                                        float* __restrict__ asrc,
                                                        float* __restrict__ adst) {
    __shared__ ushort wlds[128 * 128];   // 32 KB
    __shared__ ushort xbds[64 * 128];    // 16 KB

    const int t    = threadIdx.x;
    const int row0 = blockIdx.x * 64;

    // fused histogram: one edge per thread (grid covers E exactly)
    {
        const int e = blockIdx.x * 256 + t;
        atomicAdd(&deg[dst[e]], 1);
    }

    // stage Wt (2048 uint4), swizzled; col = byte>>8
    {
        const uint4* wg = (const uint4*)wt;
#pragma unroll
        for (int i = 0; i < 8; ++i) {
            const int idx  = t + i * 256;
            const uint4 v  = wg[idx];
            const int byte = idx * 16;
            const int swz  = byte ^ (((byte >> 8) & 7) << 4);
            *(uint4*)((char*)wlds + swz) = v;
        }
    }
    // stage x rows row0..row0+63: 2048 coalesced float4 reads -> bf16 uint2 (8 B) writes
    {
        const float4* xg = (const float4*)(x + (size_t)row0 * INF);
#pragma unroll
        for (int i = 0; i < 8; ++i) {
            const int idx  = t + i * 256;       // dest row = (idx*8)>>8
            const float4 q = xg[idx];
            uint2 v;
            v.x = pack_bf2(q.x, q.y);
            v.y = pack_bf2(q.z, q.w);
            const int byte = idx * 8;
            const int swz  = byte ^ (((byte >> 8) & 7) << 4);
            *(uint2*)((char*)xbds + swz) = v;
        }
    }

    const int w    = t >> 6;       // wave 0..3
    const int l    = t & 63;
    const int lrow = l & 15;       // A row within band / C,D col
    const int lgrp = l >> 4;       // k-chunk group

    __syncthreads();   // staging done

    // A-frags from swizzled LDS: row = w*16+lrow, frag kk covers k = kk*32+lgrp*8 .. +7
    bf16x8 afrag[4];
    {
        const int arow = w * 16 + lrow;
        const int rswz = (arow & 7) << 4;
#pragma unroll
        for (int kk = 0; kk < 4; ++kk) {
            const int byte = arow * 256 + kk * 64 + lgrp * 16;
            afrag[kk] = *(const bf16x8*)((const char*)xbds + (byte ^ rswz));
        }
    }

    f32x4 acc[8];
#pragma unroll
    for (int ct = 0; ct < 8; ++ct) acc[ct] = f32x4{0.f, 0.f, 0.f, 0.f};

#pragma unroll
    for (int ct = 0; ct < 8; ++ct) {
        const int col = ct * 16 + lrow;
#pragma unroll
        for (int kk = 0; kk < 4; ++kk) {
            const int byte = col * 256 + kk * 64 + lgrp * 16;
            const int swz  = byte ^ (((byte >> 8) & 7) << 4);
            const bf16x8 bfrag = *(const bf16x8*)((const char*)wlds + swz);
            acc[ct] = __builtin_amdgcn_mfma_f32_16x16x32_bf16(afrag[kk], bfrag, acc[ct], 0, 0, 0);
        }
    }

    // a-vector values for this lane's 8 cols: head = ct>>1, in-head offset = (ct&1)*16+lrow
    float a1v[8], a2v[8];
#pragma unroll
    for (int ct = 0; ct < 8; ++ct) {
        const int head = ct >> 1;
        const int coff = (ct & 1) * 16 + lrow;
        a1v[ct] = a[head * 2 * F + coff];
        a2v[ct] = a[head * 2 * F + F + coff];
    }

    // per-(head,row) partial dots + 16-lane butterfly
    float ph1[4][4], ph2[4][4];   // [head][r]
#pragma unroll
    for (int hd = 0; hd < 4; ++hd)
#pragma unroll
        for (int r = 0; r < 4; ++r) { ph1[hd][r] = 0.f; ph2[hd][r] = 0.f; }
#pragma unroll
    for (int ct = 0; ct < 8; ++ct) {
        const int hd = ct >> 1;
#pragma unroll
        for (int r = 0; r < 4; ++r) {
            ph1[hd][r] += acc[ct][r] * a1v[ct];
            ph2[hd][r] += acc[ct][r] * a2v[ct];
        }
    }
#pragma unroll
    for (int m = 1; m < 16; m <<= 1) {
#pragma unroll
        for (int hd = 0; hd < 4; ++hd)
#pragma unroll
            for (int r = 0; r < 4; ++r) {
                ph1[hd][r] += __shfl_xor(ph1[hd][r], m);
                ph2[hd][r] += __shfl_xor(ph2[hd][r], m);
            }
    }

    // writes (scalar hb stores; LDS-repack variant cost ~3us in R9)
#pragma unroll
    for (int r = 0; r < 4; ++r) {
        const int row = row0 + w * 16 + lgrp * 4 + r;
        const int b   = row / N;
        const int n   = row - b * N;
        const size_t hbase = ((size_t)n * B + b) * HF;
#pragma unroll
        for (int ct = 0; ct < 8; ++ct)
            hb[hbase + ct * 16 + lrow] = __float2bfloat16(acc[ct][r]);
        if (lrow == 0) {
            const size_t ai = (size_t)b * (N * H) + (size_t)n * H;   // batch-major
#pragma unroll
            for (int hd = 0; hd < 4; ++hd) {
                asrc[ai + hd] = ph1[hd][r];
                adst[ai + hd] = ph2[hd][r];
            }
        }
    }
}

// single-block scan over PADDED degrees: offsets[n] = cumsum of roundup16(deg).
// 1000 active threads x 20 nodes (N = 20000).
__global__ __launch_bounds__(1024) void scan_kernel(const int* __restrict__ deg,
                                                    int* __restrict__ offsets,
                                                    int* __restrict__ cursor) {
    __shared__ int part[1024];
    const int t = threadIdx.x;
    const bool active = (t * 20) < N;     // t < 1000

    int v[20];
    int s = 0;
    if (active) {
        const int4* dp = (const int4*)(deg + t * 20);
#pragma unroll
        for (int i = 0; i < 5; ++i) {
            int4 q = dp[i];
            v[i * 4 + 0] = (q.x + 15) & ~15;
            v[i * 4 + 1] = (q.y + 15) & ~15;
            v[i * 4 + 2] = (q.z + 15) & ~15;
            v[i * 4 + 3] = (q.w + 15) & ~15;
            s += v[i * 4] + v[i * 4 + 1] + v[i * 4 + 2] + v[i * 4 + 3];
        }
    }
    part[t] = s;
    __syncthreads();
    for (int off = 1; off < 1024; off <<= 1) {
        int u = (t >= off) ? part[t - off] : 0;
        __syncthreads();
        part[t] += u;
        __syncthreads();
    }
    if (active) {
        int run = (t == 0) ? 0 : part[t - 1];
        int o[20];
#pragma unroll
        for (int i = 0; i < 20; ++i) { o[i] = run; run += v[i]; }
        int4* op = (int4*)(offsets + t * 20);
        int4* cp = (int4*)(cursor + t * 20);
#pragma unroll
        for (int i = 0; i < 5; ++i) {
            int4 q = {o[i * 4 + 0], o[i * 4 + 1], o[i * 4 + 2], o[i * 4 + 3]};
            op[i] = q;
            cp[i] = q;
        }
    }
}

__global__ __launch_bounds__(256) void fill_kernel(const int* __restrict__ ei,
                                                   int* __restrict__ cursor,
                                                   int* __restrict__ csr) {
    int e = blockIdx.x * 256 + threadIdx.x;
    if (e >= E) return;
    const int s = ei[e];          // src row
    const int d = ei[E + e];      // dst row
    const int pos = atomicAdd(&cursor[d], 1);
    csr[pos] = s;
}

// ---------------------------------------------------------------- gather/aggregate (bf16 h, XCD-affine)
// Grid 20000 blocks (= B * N/4); block i: batch b = (i%8)>>1, node-quad = (i>>3)*2 + (i&1).
// Round-robin blockIdx->XCD (%8) pins each batch to one XCD pair -> per-XCD L2
// working set 5.1 MB (R11-verified: FETCH 152 -> 75 MB).
// Wave = one (node, batch). Lane l: edge-slot g = l>>4, feature octet fq = l&15, head = fq>>2.
// CSR is padded per node to x16 with zeros (safe index), so the 16-edge/iter loop needs
// no clamp; masked by e=0. Accumulate in f32x2 (v_pk_fma_f32 target). 4 chains/lane.
__global__ __launch_bounds__(256) void gather_kernel(const __hip_bfloat16* __restrict__ hb,
                                                     const float* __restrict__ asrc,
                                                     const float* __restrict__ adst,
                                                     const int* __restrict__ offsets,
                                                     const int* __restrict__ deg,
                                                     const int* __restrict__ csr,
                                                     float* __restrict__ out) {
    const int t  = threadIdx.x;
    const int k  = blockIdx.x & 7;
    const int b  = k >> 1;                         // batch pinned to XCD pair {2b,2b+1}
    const int n  = ((blockIdx.x >> 3) * 2 + (k & 1)) * 4 + (t >> 6);
    const int l  = t & 63;
    const int g  = l >> 4;                         // edge slot 0..3
    const int fq = l & 15;                         // feature octet
    const int hh = fq >> 2;

    const uint4* hu = (const uint4*)hb;            // idx = s*64 + rowq
    const int rowq = b * 16 + fq;
    const size_t abase = (size_t)b * (N * H);      // batch-major alpha
    const float ad = adst[abase + (size_t)n * H + hh];
    const int j0 = offsets[n];
    const int d  = deg[n];
    const int j1 = j0 + d;
    const int iters = (d + 15) >> 4;

    f32x2 acc2[4];
#pragma unroll
    for (int i = 0; i < 4; ++i) acc2[i] = f32x2{0.f, 0.f};
    float den = 0.f;

    for (int it = 0; it < iters; ++it) {
        const int jb = j0 + it * 16 + g;
        int   sv[4];
        float lv[4];
        uint4 hv[4];
#pragma unroll
        for (int c = 0; c < 4; ++c) sv[c] = csr[jb + c * 4];
#pragma unroll
        for (int c = 0; c < 4; ++c) lv[c] = asrc[abase + (size_t)sv[c] * H + hh];
#pragma unroll
        for (int c = 0; c < 4; ++c) hv[c] = hu[(size_t)sv[c] * 64 + rowq];

#pragma unroll
        for (int c = 0; c < 4; ++c) {
            float tt = lv[c] + ad;
            tt = (tt >= 0.f) ? tt : 0.2f * tt;
            const float e = (jb + c * 4 < j1) ? __expf(tt) : 0.f;
            den += e;
            const f32x2 e2 = {e, e};
            acc2[0] += e2 * unp2(hv[c].x);
            acc2[1] += e2 * unp2(hv[c].y);
            acc2[2] += e2 * unp2(hv[c].z);
            acc2[3] += e2 * unp2(hv[c].w);
        }
    }

    // reduce across the 4 edge slots (lanes sharing fq)
    float ac[8] = {acc2[0].x, acc2[0].y, acc2[1].x, acc2[1].y,
                   acc2[2].x, acc2[2].y, acc2[3].x, acc2[3].y};
    den += __shfl_xor(den, 16);
    den += __shfl_xor(den, 32);
#pragma unroll
    for (int i = 0; i < 8; ++i) {
        ac[i] += __shfl_xor(ac[i], 16);
        ac[i] += __shfl_xor(ac[i], 32);
    }

    if (g == 0) {
        const float inv = 1.0f / (den + 1e-10f);
        float4 o0 = {ac[0] * inv, ac[1] * inv, ac[2] * inv, ac[3] * inv};
        float4 o1 = {ac[4] * inv, ac[5] * inv, ac[6] * inv, ac[7] * inv};
        float4* op = (float4*)(out + ((size_t)b * N + n) * HF + fq * 8);
        op[0] = o0;
        op[1] = o1;
    }
}

// ---------------------------------------------------------------- launch
extern "C" void kernel_launch(void* const* d_in, const int* in_sizes, int n_in,
                              void* d_out, int out_size, void* d_ws, size_t ws_size,
                              hipStream_t stream) {
    const float* x   = (const float*)d_in[0];
    const int*   ei  = (const int*)d_in[1];     // int32 (harness converts int64 -> int32)
    const float* W   = (const float*)d_in[2];
    const float* a   = (const float*)d_in[3];
    float*       out = (float*)d_out;

    // workspace carve (~26.3 MB total)
    char* p = (char*)d_ws;
    __hip_bfloat16* hb = (__hip_bfloat16*)p; p += (size_t)B * N * HF * sizeof(__hip_bfloat16); // 20,480,000 B
    float* asrc = (float*)p; p += (size_t)N * B * H * sizeof(float);    // 1,280,000 B
    float* adst = (float*)p; p += (size_t)N * B * H * sizeof(float);    // 1,280,000 B
    int* deg     = (int*)p;  p += 80128;
    int* offsets = (int*)p;  p += 80128;
    int* cursor  = (int*)p;  p += 80128;
    int* csr     = (int*)p;  p += (size_t)CSRP * sizeof(int);           // 2,480,000 B
    __hip_bfloat16* wt = (__hip_bfloat16*)p; p += (size_t)HF * INF * sizeof(__hip_bfloat16); // 32,768 B

    // 5 dispatches total
    initz_kernel<<<(CSRP / 4 + 255) / 256, 256, 0, stream>>>(W, wt, deg, csr);
    gemm_mfma_kernel<<<(B * N) / 64, 256, 0, stream>>>(x, wt, a, ei + E, deg, hb, asrc, adst);
    scan_kernel<<<1, 1024, 0, stream>>>(deg, offsets, cursor);
    fill_kernel<<<(E + 255) / 256, 256, 0, stream>>>(ei, cursor, csr);
    gather_kernel<<<(N * B) / 4, 256, 0, stream>>>(hb, asrc, adst, offsets, deg, csr, out);
}